// Round 6
// baseline (467.028 us; speedup 1.0000x reference)
//
#include <hip/hip_runtime.h>
#include <stdint.h>

#define AS1 __attribute__((address_space(1)))
#define AS3 __attribute__((address_space(3)))

typedef float floatx4 __attribute__((ext_vector_type(4)));
typedef __bf16 bf16x8 __attribute__((ext_vector_type(8)));
typedef unsigned short ushort8 __attribute__((ext_vector_type(8)));

__device__ __forceinline__ unsigned short f2bf(float x) {
    union { float f; unsigned int u; } v; v.f = x;
    unsigned int r = v.u + 0x7fffu + ((v.u >> 16) & 1u);   // round-to-nearest-even
    return (unsigned short)(r >> 16);
}

// ---------------- fused prep: wn(v1) | wn(v2) | qhraw  (independent block ranges) ----------
__global__ __launch_bounds__(256) void prep_kernel(
        const float* __restrict__ v1, const float* __restrict__ g1,
        unsigned short* __restrict__ W1, float* __restrict__ scale1,
        const float* __restrict__ v2, const float* __restrict__ g2,
        unsigned short* __restrict__ W2, float* __restrict__ scale2,
        const float* __restrict__ qf, float* __restrict__ qhraw) {
    const int blk = blockIdx.x;
    const int t = threadIdx.x;
    __shared__ float red[4];
    __shared__ float scale_s;
    __shared__ float qs[32][128];

    if (blk < 2048) {
        const float* v; const float* g; unsigned short* W; float* so; int K; int row;
        if (blk < 1024) { v = v1; g = g1; W = W1; so = scale1; K = 3072; row = blk; }
        else            { v = v2; g = g2; W = W2; so = scale2; K = 1024; row = blk - 1024; }
        const float* vr = v + (size_t)row * K;
        float s = 0.f;
        for (int c = t; c < K; c += 256) { float x = vr[c]; s += x * x; }
        #pragma unroll
        for (int o = 32; o > 0; o >>= 1) s += __shfl_down(s, o, 64);
        if ((t & 63) == 0) red[t >> 6] = s;
        __syncthreads();
        if (t == 0) {
            float sc = g[row] * rsqrtf(red[0] + red[1] + red[2] + red[3]);
            scale_s = sc;
            so[row] = sc;
        }
        __syncthreads();
        float scale = scale_s;
        unsigned short* Wr = W + (size_t)row * K;
        for (int c = t; c < K; c += 256) Wr[c] = f2bf(vr[c] * scale);
    } else {
        const int bq = blk - 2048;
        const int dblk = bq >> 3, ks = bq & 7;
        for (int i = t; i < 4096; i += 256) {
            int b = i >> 7, kk = i & 127;
            qs[b][kk] = qf[b * 1024 + ks * 128 + kk];
        }
        __syncthreads();
        const int dLoc = t >> 1, khalf = t & 1;
        const int d = dblk * 128 + dLoc;
        const float* vp = v1 + (size_t)d * 3072 + 2048 + ks * 128 + khalf * 64;
        float acc[32];
        #pragma unroll
        for (int b = 0; b < 32; b++) acc[b] = 0.f;
        for (int j = 0; j < 64; j++) {
            float v = vp[j];
            const int kk = khalf * 64 + j;
            #pragma unroll
            for (int b = 0; b < 32; b++) acc[b] += v * qs[b][kk];
        }
        #pragma unroll
        for (int b = 0; b < 32; b++) {
            float tot = acc[b] + __shfl_xor(acc[b], 1, 64);
            if (khalf == 0) atomicAdd(&qhraw[b * 1024 + d], tot);
        }
    }
}

// ---- stage one 128-row half-tile (rows rowbase..rowbase+127, BK=64 bf16) into LDS ----
__device__ __forceinline__ void stage_half_g(
        const unsigned short* __restrict__ gbase, int ldx,
        unsigned short* lbuf, int rowbase, int k0, int srow, int schunk) {
    #pragma unroll
    for (int p = 0; p < 2; p++) {
        const int r = rowbase + p * 64 + srow;
        const unsigned short* src = gbase + (size_t)r * ldx + (k0 + ((schunk ^ (srow & 7)) * 8));
        __builtin_amdgcn_global_load_lds((AS1 void*)src,
                                         (AS3 void*)(&lbuf[r * 64 + schunk * 8]),
                                         16, 0, 0);
    }
}

// ---------------- 256x256-tile 4-phase NT GEMM: C[m,n] = sum_k A[m,k]*B[n,k] ----------------
// 512 threads = 8 waves (2M x 4N), BK=64, double-buffered 128 KiB LDS, 16x16x32 MFMA.
// AF32=1: fp32 A fused convert (reg-stage: float4 loads -> f2bf -> ds_write_b128, swizzled
// layout). A-pipeline spread across phases with exact FIFO vmcnt bookkeeping
// (LOAD = 4 loads/thread, DMA = 2 ops/thread):
//   P1(t): issue LOAD regA1 <- A-h1(t+1)            [outstanding: Ah0(4), Ah1(4)]
//   P2(t): DMA B-h0(t+1) -> 10; vmcnt(6) drains Ah0 (2-phase cover); WRITE regA0
//   P3(t): DMA B-h1(t+1) -> 8;  vmcnt(4) drains Ah1 (2-phase cover); WRITE regA1
//   P4(t): LOAD regA0 <- A-h0(t+2) -> 8; vmcnt(4) drains B(t+1) (R2-proven cadence)
// ds_writes drain at each phase's lgkm0; two barriers separate them from P1(t+1) reads.
template<int AF32, int QH, int RELU, int OUT_BF16>
__global__ __launch_bounds__(512, 2) void gemm256_kernel(
        const void* __restrict__ Av,
        const unsigned short* __restrict__ Bm,   // [Nd, ldb] row-major bf16
        const float* __restrict__ bias,
        const float* __restrict__ qh,            // [32,1024] fp32 raw when QH
        const float* __restrict__ qscale,        // scale1 when QH
        void* __restrict__ Cout,
        int K, int lda, int ldb, int ldc) {
    const int t = threadIdx.x;
    // XCD-bijective remap of the flat workgroup id (nwg divisible by 8)
    const int nx = gridDim.x;
    const int nwg = nx * gridDim.y;
    const int orig = blockIdx.y * nx + blockIdx.x;
    const int q = nwg >> 3;
    const int swz = (orig & 7) * q + (orig >> 3);
    const int tileM = (swz / nx) * 256;
    const int tileN = (swz % nx) * 256;
    const unsigned short* At = AF32 ? nullptr
                                    : ((const unsigned short*)Av + (size_t)tileM * lda);
    const float* Af = AF32 ? ((const float*)Av + (size_t)tileM * lda) : nullptr;
    const unsigned short* Bt = Bm + (size_t)tileN * ldb;

    __shared__ unsigned short As[2][256 * 64];
    __shared__ unsigned short Bs[2][256 * 64];

    const int lane = t & 63;
    const int wv = t >> 6;           // 0..7
    const int wm = (wv & 1) * 128;   // wave's 128-row M base
    const int wn = (wv >> 1) * 64;   // wave's 64-row N base
    const int lr = lane & 15;
    const int koff0 = (((lane >> 4) + 0) ^ (lane & 7)) * 8;
    const int koff1 = (((lane >> 4) + 4) ^ (lane & 7)) * 8;

    const int srow = t >> 3;         // 0..63 staging row within 64-row pass
    const int schunk = t & 7;        // staging 8-elem chunk
    const int csrc = (schunk ^ (srow & 7)) * 8;   // swizzled source column

    floatx4 acc[8][4];
    const floatx4 fzero = {0.f, 0.f, 0.f, 0.f};
    #pragma unroll
    for (int i = 0; i < 8; i++)
        #pragma unroll
        for (int j = 0; j < 4; j++) acc[i][j] = fzero;

    const int NT = K >> 6;           // K-tiles (>= 2 for all call sites)

    float4 regA0[4], regA1[4];       // AF32: in-flight fp32 A half-tiles (h0 / h1)

#define LOAD_A_HALF(reg, rowbase, kreq)                                          \
    { const float* s_ = Af + (size_t)((rowbase) + srow) * lda + ((kreq) + csrc); \
      reg[0] = *(const float4*)(s_);                                             \
      reg[1] = *(const float4*)(s_ + 4);                                         \
      const float* s1_ = s_ + (size_t)64 * lda;                                  \
      reg[2] = *(const float4*)(s1_);                                            \
      reg[3] = *(const float4*)(s1_ + 4); }

#define WRITE_A_HALF(reg, lbuf, rowbase)                                         \
    { ushort8 o_;                                                                \
      o_[0] = f2bf(reg[0].x); o_[1] = f2bf(reg[0].y);                            \
      o_[2] = f2bf(reg[0].z); o_[3] = f2bf(reg[0].w);                            \
      o_[4] = f2bf(reg[1].x); o_[5] = f2bf(reg[1].y);                            \
      o_[6] = f2bf(reg[1].z); o_[7] = f2bf(reg[1].w);                            \
      *(ushort8*)(&lbuf[((rowbase) + srow) * 64 + schunk * 8]) = o_;             \
      ushort8 o2_;                                                               \
      o2_[0] = f2bf(reg[2].x); o2_[1] = f2bf(reg[2].y);                          \
      o2_[2] = f2bf(reg[2].z); o2_[3] = f2bf(reg[2].w);                          \
      o2_[4] = f2bf(reg[3].x); o2_[5] = f2bf(reg[3].y);                          \
      o2_[6] = f2bf(reg[3].z); o2_[7] = f2bf(reg[3].w);                          \
      *(ushort8*)(&lbuf[((rowbase) + 64 + srow) * 64 + schunk * 8]) = o2_; }

    // ---- prologue ----
    if (AF32) {
        LOAD_A_HALF(regA0, 0, 0);                       // 4 loads (oldest)
        LOAD_A_HALF(regA1, 128, 0);                     // 4 loads
        stage_half_g(Bt, ldb, Bs[0], 0,   0, srow, schunk);   // 2 DMA
        stage_half_g(Bt, ldb, Bs[0], 128, 0, srow, schunk);   // 2 DMA
        asm volatile("s_waitcnt vmcnt(4)" ::: "memory");      // 8 A-loads landed
        WRITE_A_HALF(regA0, As[0], 0);
        WRITE_A_HALF(regA1, As[0], 128);
        if (NT > 1) {
            LOAD_A_HALF(regA0, 0, 64);                        // A-h0(tile1) in flight
            asm volatile("s_waitcnt vmcnt(4)" ::: "memory");  // 4 B-DMAs landed
        } else {
            asm volatile("s_waitcnt vmcnt(0)" ::: "memory");
        }
        asm volatile("s_waitcnt lgkmcnt(0)" ::: "memory");    // ds_writes visible
    } else {
        stage_half_g(At, lda, As[0], 0,   0, srow, schunk);
        stage_half_g(At, lda, As[0], 128, 0, srow, schunk);
        stage_half_g(Bt, ldb, Bs[0], 0,   0, srow, schunk);
        stage_half_g(Bt, ldb, Bs[0], 128, 0, srow, schunk);
        stage_half_g(At, lda, As[1], 0,  64, srow, schunk);
        asm volatile("s_waitcnt vmcnt(2)" ::: "memory");
    }
    __builtin_amdgcn_s_barrier();

    bf16x8 aR[4][2], bR0[2][2], bR1[2][2];

    for (int tt = 0; tt < NT; ++tt) {
        const int c = tt & 1;
        const unsigned short* Ac = As[c];
        const unsigned short* Bc = Bs[c];
        const int nc = (tt + 1) & 1;
        const int k1 = (tt + 1) << 6;

        // ---- P1: read A-frags 0..3 + B-frags 0..1; issue A-h1(t+1) ----
        #pragma unroll
        for (int i = 0; i < 4; i++) {
            aR[i][0] = *(const bf16x8*)(&Ac[(wm + i * 16 + lr) * 64 + koff0]);
            aR[i][1] = *(const bf16x8*)(&Ac[(wm + i * 16 + lr) * 64 + koff1]);
        }
        #pragma unroll
        for (int j = 0; j < 2; j++) {
            bR0[j][0] = *(const bf16x8*)(&Bc[(wn + j * 16 + lr) * 64 + koff0]);
            bR0[j][1] = *(const bf16x8*)(&Bc[(wn + j * 16 + lr) * 64 + koff1]);
        }
        if (tt + 1 < NT) {
            if (AF32) { LOAD_A_HALF(regA1, 128, k1); }
            else      { stage_half_g(At, lda, As[nc], 128, k1, srow, schunk); }
        }
        __builtin_amdgcn_s_barrier();
        asm volatile("s_waitcnt lgkmcnt(0)" ::: "memory");
        __builtin_amdgcn_s_setprio(1);
        #pragma unroll
        for (int i = 0; i < 4; i++)
            #pragma unroll
            for (int j = 0; j < 2; j++)
                #pragma unroll
                for (int ks = 0; ks < 2; ks++)
                    acc[i][j] = __builtin_amdgcn_mfma_f32_16x16x32_bf16(
                        aR[i][ks], bR0[j][ks], acc[i][j], 0, 0, 0);
        __builtin_amdgcn_s_setprio(0);
        __builtin_amdgcn_s_barrier();

        // ---- P2: read B-frags 2..3; DMA B-h0(t+1); AF32: drain A-h0, write it ----
        #pragma unroll
        for (int j = 0; j < 2; j++) {
            bR1[j][0] = *(const bf16x8*)(&Bc[(wn + (j + 2) * 16 + lr) * 64 + koff0]);
            bR1[j][1] = *(const bf16x8*)(&Bc[(wn + (j + 2) * 16 + lr) * 64 + koff1]);
        }
        if (tt + 1 < NT) {
            stage_half_g(Bt, ldb, Bs[nc], 0, k1, srow, schunk);
            if (AF32) {
                asm volatile("s_waitcnt vmcnt(6)" ::: "memory");   // A-h0(t+1) landed
                WRITE_A_HALF(regA0, As[nc], 0);
            }
        }
        __builtin_amdgcn_s_barrier();
        asm volatile("s_waitcnt lgkmcnt(0)" ::: "memory");
        __builtin_amdgcn_s_setprio(1);
        #pragma unroll
        for (int i = 0; i < 4; i++)
            #pragma unroll
            for (int j = 0; j < 2; j++)
                #pragma unroll
                for (int ks = 0; ks < 2; ks++)
                    acc[i][j + 2] = __builtin_amdgcn_mfma_f32_16x16x32_bf16(
                        aR[i][ks], bR1[j][ks], acc[i][j + 2], 0, 0, 0);
        __builtin_amdgcn_s_setprio(0);
        __builtin_amdgcn_s_barrier();

        // ---- P3: read A-frags 4..7; DMA B-h1(t+1); AF32: drain A-h1, write it ----
        #pragma unroll
        for (int i = 0; i < 4; i++) {
            aR[i][0] = *(const bf16x8*)(&Ac[(wm + (i + 4) * 16 + lr) * 64 + koff0]);
            aR[i][1] = *(const bf16x8*)(&Ac[(wm + (i + 4) * 16 + lr) * 64 + koff1]);
        }
        if (tt + 1 < NT) {
            stage_half_g(Bt, ldb, Bs[nc], 128, k1, srow, schunk);
            if (AF32) {
                asm volatile("s_waitcnt vmcnt(4)" ::: "memory");   // A-h1(t+1) landed
                WRITE_A_HALF(regA1, As[nc], 128);
            }
        }
        __builtin_amdgcn_s_barrier();
        asm volatile("s_waitcnt lgkmcnt(0)" ::: "memory");
        __builtin_amdgcn_s_setprio(1);
        #pragma unroll
        for (int i = 0; i < 4; i++)
            #pragma unroll
            for (int j = 0; j < 2; j++)
                #pragma unroll
                for (int ks = 0; ks < 2; ks++)
                    acc[i + 4][j + 2] = __builtin_amdgcn_mfma_f32_16x16x32_bf16(
                        aR[i][ks], bR1[j][ks], acc[i + 4][j + 2], 0, 0, 0);
        __builtin_amdgcn_s_setprio(0);
        __builtin_amdgcn_s_barrier();

        // ---- P4: issue A-h0(t+2); counted vmcnt (drains B(t+1)); MFMA ----
        if (AF32) {
            if (tt + 2 < NT) {
                LOAD_A_HALF(regA0, 0, (tt + 2) << 6);
                asm volatile("s_waitcnt vmcnt(4)" ::: "memory");   // B(t+1) landed
            } else if (tt + 1 < NT) {
                asm volatile("s_waitcnt vmcnt(0)" ::: "memory");   // tail drain
            }
        } else {
            if (tt + 2 < NT) {
                stage_half_g(At, lda, As[c], 0, (tt + 2) << 6, srow, schunk);
                asm volatile("s_waitcnt vmcnt(2)" ::: "memory");
            } else if (tt + 1 < NT) {
                asm volatile("s_waitcnt vmcnt(0)" ::: "memory");
            }
        }
        __builtin_amdgcn_s_barrier();
        __builtin_amdgcn_s_setprio(1);
        #pragma unroll
        for (int i = 0; i < 4; i++)
            #pragma unroll
            for (int j = 0; j < 2; j++)
                #pragma unroll
                for (int ks = 0; ks < 2; ks++)
                    acc[i + 4][j] = __builtin_amdgcn_mfma_f32_16x16x32_bf16(
                        aR[i][ks], bR0[j][ks], acc[i + 4][j], 0, 0, 0);
        __builtin_amdgcn_s_setprio(0);
        __builtin_amdgcn_s_barrier();
    }

    // epilogue: D row (M) = (lane>>4)*4 + r, col (N) = lane&15  [m89-verified layout]
    unsigned short* Cb = (unsigned short*)Cout;
    float* Cf = (float*)Cout;
    const float* qhr = QH ? (qh + (size_t)(tileM >> 9) * 1024) : nullptr;
    const int rowHalf = (lane >> 4) * 4;
    #pragma unroll
    for (int j = 0; j < 4; j++) {
        const int col = tileN + wn + j * 16 + lr;
        float bv = RELU ? bias[col] : 0.0f;
        if (QH) bv += qscale[col] * qhr[col];
        #pragma unroll
        for (int i = 0; i < 8; i++) {
            const int row0 = tileM + wm + i * 16 + rowHalf;
            #pragma unroll
            for (int r = 0; r < 4; r++) {
                float val = acc[i][j][r] + bv;
                if (RELU) val = fmaxf(val, 0.0f);
                const size_t off = (size_t)(row0 + r) * ldc + col;
                if (OUT_BF16) Cb[off] = f2bf(val);
                else          Cf[off] = val;
            }
        }
    }
#undef LOAD_A_HALF
#undef WRITE_A_HALF
}

// ---------------- 128x128 NT GEMM (m97 structure) — kept for the batched S GEMM ----------------
template<int QH, int RELU, int OUT_BF16>
__global__ __launch_bounds__(256) void gemm_bt_kernel(
        const unsigned short* __restrict__ A,
        const unsigned short* __restrict__ Bm,
        const float* __restrict__ bias,
        const float* __restrict__ qh,
        void* __restrict__ Cout,
        int K, int lda, int ldb, int ldc,
        long strideA, long strideB, long strideC) {
    const int t = threadIdx.x;
    const int bz = blockIdx.z;
    const int tileM = blockIdx.y * 128;
    const int tileN = blockIdx.x * 128;
    const unsigned short* Abase = A + (size_t)bz * strideA;
    const unsigned short* Bbase = Bm + (size_t)bz * strideB;

    __shared__ unsigned short As[128 * 64];
    __shared__ unsigned short Bs[128 * 64];

    const int lane = t & 63;
    const int wv = t >> 6;
    const int wm = (wv & 1) * 64;
    const int wn = (wv >> 1) * 64;
    const int lr = lane & 15;

    const int koff0 = (((lane >> 4) + 0) ^ (lane & 7)) * 8;
    const int koff1 = (((lane >> 4) + 4) ^ (lane & 7)) * 8;

    floatx4 acc[4][4];
    const floatx4 fzero = {0.f, 0.f, 0.f, 0.f};
    #pragma unroll
    for (int i = 0; i < 4; i++)
        #pragma unroll
        for (int j = 0; j < 4; j++) acc[i][j] = fzero;

    const int rowQ = t >> 3;
    const int colSw = ((t & 7) ^ (rowQ & 7)) * 8;

    for (int k0 = 0; k0 < K; k0 += 64) {
        #pragma unroll
        for (int p = 0; p < 4; p++) {
            const int r = p * 32 + rowQ;
            const unsigned short* srcA = Abase + (size_t)(tileM + r) * lda + (k0 + colSw);
            __builtin_amdgcn_global_load_lds((AS1 void*)srcA,
                                             (AS3 void*)(&As[p * 2048 + t * 8]),
                                             16, 0, 0);
        }
        #pragma unroll
        for (int p = 0; p < 4; p++) {
            const int r = p * 32 + rowQ;
            const unsigned short* srcB = Bbase + (size_t)(tileN + r) * ldb + (k0 + colSw);
            __builtin_amdgcn_global_load_lds((AS1 void*)srcB,
                                             (AS3 void*)(&Bs[p * 2048 + t * 8]),
                                             16, 0, 0);
        }
        __syncthreads();

        #pragma unroll
        for (int ks = 0; ks < 2; ks++) {
            const int koff = ks ? koff1 : koff0;
            bf16x8 af[4], bfr[4];
            #pragma unroll
            for (int i = 0; i < 4; i++)
                af[i] = *(const bf16x8*)(&As[(wm + i * 16 + lr) * 64 + koff]);
            #pragma unroll
            for (int j = 0; j < 4; j++)
                bfr[j] = *(const bf16x8*)(&Bs[(wn + j * 16 + lr) * 64 + koff]);
            #pragma unroll
            for (int i = 0; i < 4; i++)
                #pragma unroll
                for (int j = 0; j < 4; j++)
                    acc[i][j] = __builtin_amdgcn_mfma_f32_16x16x32_bf16(
                        af[i], bfr[j], acc[i][j], 0, 0, 0);
        }
        __syncthreads();
    }

    unsigned short* Cb = (unsigned short*)Cout + (size_t)bz * strideC;
    float* Cf = (float*)Cout + (size_t)bz * strideC;
    const float* qhr = QH ? (qh + (size_t)(tileM >> 9) * 1024) : nullptr;
    const int rowHalf = (lane >> 4) * 4;
    #pragma unroll
    for (int j = 0; j < 4; j++) {
        const int col = tileN + wn + j * 16 + lr;
        float bv = RELU ? bias[col] : 0.0f;
        if (QH) bv += qhr[col];
        #pragma unroll
        for (int i = 0; i < 4; i++) {
            const int row0 = tileM + wm + i * 16 + rowHalf;
            #pragma unroll
            for (int r = 0; r < 4; r++) {
                float val = acc[i][j][r] + bv;
                if (RELU) val = fmaxf(val, 0.0f);
                const size_t off = (size_t)(row0 + r) * ldc + col;
                if (OUT_BF16) Cb[off] = f2bf(val);
                else          Cf[off] = val;
            }
        }
    }
}

// ---------------- gather: out[e] = S_flat[idx[e]] ----------------
__global__ __launch_bounds__(256) void gather_kernel(
        const float* __restrict__ S, const int* __restrict__ idx,
        float* __restrict__ out, int E) {
    int e = blockIdx.x * 256 + threadIdx.x;
    if (e < E) out[e] = S[idx[e]];
}

extern "C" void kernel_launch(void* const* d_in, const int* in_sizes, int n_in,
                              void* d_out, int out_size, void* d_ws, size_t ws_size,
                              hipStream_t stream) {
    const float* node = (const float*)d_in[0];   // [32,512,2048]
    const float* qf   = (const float*)d_in[1];   // [32,1024]
    const int*   idx  = (const int*)d_in[2];     // [1048576]
    const float* v1   = (const float*)d_in[3];   // [1024,3072]
    const float* g1   = (const float*)d_in[4];
    const float* b1   = (const float*)d_in[5];
    const float* v2   = (const float*)d_in[6];   // [1024,1024]
    const float* g2   = (const float*)d_in[7];
    const float* b2   = (const float*)d_in[8];
    float* out = (float*)d_out;

    // workspace carve (all offsets 256B aligned)
    char* ws = (char*)d_ws;
    unsigned short* W1     = (unsigned short*)(ws);              // 6,291,456 B
    unsigned short* W2     = (unsigned short*)(ws + 6291456);    // 2,097,152 B
    float*          S      = (float*)(ws + 8388608);             // 33,554,432 B
    unsigned short* h1     = (unsigned short*)(ws + 75563008);   // 33,554,432 B
    unsigned short* h2     = (unsigned short*)(ws + 109117440);  // 33,554,432 B
    float*          scale1 = (float*)(ws + 142671872);           // 4,096 B
    float*          scale2 = (float*)(ws + 142675968);           // 4,096 B
    float*          qh     = (float*)(ws + 142680064);           // 131,072 B (raw, unscaled)

    // prep: fused {weight-norm x2, folded q@W1b^T (raw)}
    hipMemsetAsync(qh, 0, 131072, stream);
    prep_kernel<<<2112, 256, 0, stream>>>(v1, g1, W1, scale1,
                                          v2, g2, W2, scale2, qf, qh);

    // h1 = relu(nodes_fp32 @ W1a^T + scale1*qhraw[b] + b1)   M=16384 N=1024 K=2048
    gemm256_kernel<1, 1, 1, 1><<<dim3(4, 64), 512, 0, stream>>>(
        node, W1, b1, qh, scale1, h1, 2048, 2048, 3072, 1024);
    // h2 = relu(h1 @ W2^T + b2)                              M=16384 N=1024 K=1024
    gemm256_kernel<0, 0, 1, 1><<<dim3(4, 64), 512, 0, stream>>>(
        h1, W2, b2, nullptr, nullptr, h2, 1024, 1024, 1024, 1024);
    // S[b] = h2[b] @ h2[b]^T                                 batched 512x512, K=1024, fp32 out
    gemm_bt_kernel<0, 0, 0><<<dim3(4, 4, 32), 256, 0, stream>>>(
        h2, h2, nullptr, nullptr, S, 1024, 1024, 1024, 512,
        512L * 1024L, 512L * 1024L, 512L * 512L);
    // gather
    gather_kernel<<<4096, 256, 0, stream>>>(S, idx, out, 1048576);
}

// Round 8
// 408.478 us; speedup vs baseline: 1.1433x; 1.1433x over previous
//
#include <hip/hip_runtime.h>
#include <stdint.h>

#define AS1 __attribute__((address_space(1)))
#define AS3 __attribute__((address_space(3)))

typedef float floatx4 __attribute__((ext_vector_type(4)));
typedef __bf16 bf16x8 __attribute__((ext_vector_type(8)));

__device__ __forceinline__ unsigned short f2bf(float x) {
    union { float f; unsigned int u; } v; v.f = x;
    unsigned int r = v.u + 0x7fffu + ((v.u >> 16) & 1u);   // round-to-nearest-even
    return (unsigned short)(r >> 16);
}

// ---------------- fused prep: wn(v1) | wn(v2) | qhraw | cvt(node->bf16) ----------------
// blocks 0..1023   : weight_norm rows of v1 -> W1 (bf16), scale1
// blocks 1024..2047: weight_norm rows of v2 -> W2 (bf16), scale2
// blocks 2048..2111: qhraw[b,d] = sum_k qf[b,k]*v1[d,2048+k] (unscaled, atomic partials)
// blocks 2112..6207: fp32 -> bf16 convert of node feats (grid-stride, float4 x ushort4)
__global__ __launch_bounds__(256) void prep_kernel(
        const float* __restrict__ v1, const float* __restrict__ g1,
        unsigned short* __restrict__ W1, float* __restrict__ scale1,
        const float* __restrict__ v2, const float* __restrict__ g2,
        unsigned short* __restrict__ W2, float* __restrict__ scale2,
        const float* __restrict__ qf, float* __restrict__ qhraw,
        const float* __restrict__ node, unsigned short* __restrict__ nodesB) {
    const int blk = blockIdx.x;
    const int t = threadIdx.x;
    __shared__ float red[4];
    __shared__ float scale_s;
    __shared__ float qs[32][128];

    if (blk >= 2112) {
        // ---- cvt: 33,554,432 floats, 4096 blocks, 8 passes of float4 ----
        long i = ((long)(blk - 2112) * 256 + t) * 4;
        const long stride = 4096L * 256 * 4;
        for (; i < 33554432L; i += stride) {
            float4 v = *(const float4*)(node + i);
            ushort4 o;
            o.x = f2bf(v.x); o.y = f2bf(v.y); o.z = f2bf(v.z); o.w = f2bf(v.w);
            *(ushort4*)(nodesB + i) = o;
        }
    } else if (blk < 2048) {
        const float* v; const float* g; unsigned short* W; float* so; int K; int row;
        if (blk < 1024) { v = v1; g = g1; W = W1; so = scale1; K = 3072; row = blk; }
        else            { v = v2; g = g2; W = W2; so = scale2; K = 1024; row = blk - 1024; }
        const float* vr = v + (size_t)row * K;
        float s = 0.f;
        for (int c = t; c < K; c += 256) { float x = vr[c]; s += x * x; }
        #pragma unroll
        for (int o = 32; o > 0; o >>= 1) s += __shfl_down(s, o, 64);
        if ((t & 63) == 0) red[t >> 6] = s;
        __syncthreads();
        if (t == 0) {
            float sc = g[row] * rsqrtf(red[0] + red[1] + red[2] + red[3]);
            scale_s = sc;
            so[row] = sc;
        }
        __syncthreads();
        float scale = scale_s;
        unsigned short* Wr = W + (size_t)row * K;
        for (int c = t; c < K; c += 256) Wr[c] = f2bf(vr[c] * scale);
    } else {
        const int bq = blk - 2048;
        const int dblk = bq >> 3, ks = bq & 7;
        for (int i = t; i < 4096; i += 256) {
            int b = i >> 7, kk = i & 127;
            qs[b][kk] = qf[b * 1024 + ks * 128 + kk];
        }
        __syncthreads();
        const int dLoc = t >> 1, khalf = t & 1;
        const int d = dblk * 128 + dLoc;
        const float* vp = v1 + (size_t)d * 3072 + 2048 + ks * 128 + khalf * 64;
        float acc[32];
        #pragma unroll
        for (int b = 0; b < 32; b++) acc[b] = 0.f;
        for (int j = 0; j < 64; j++) {
            float v = vp[j];
            const int kk = khalf * 64 + j;
            #pragma unroll
            for (int b = 0; b < 32; b++) acc[b] += v * qs[b][kk];
        }
        #pragma unroll
        for (int b = 0; b < 32; b++) {
            float tot = acc[b] + __shfl_xor(acc[b], 1, 64);
            if (khalf == 0) atomicAdd(&qhraw[b * 1024 + d], tot);
        }
    }
}

// ---- stage one 128-row half-tile (rows rowbase..rowbase+127, BK=64 bf16) into LDS ----
// linear LDS dest (wave-uniform base + lane*16B), XOR chunk swizzle applied on the
// GLOBAL source column (chunk ^ (row&7)) so the read side can use swizzled offsets.
__device__ __forceinline__ void stage_half_g(
        const unsigned short* __restrict__ gbase, int ldx,
        unsigned short* lbuf, int rowbase, int k0, int srow, int schunk) {
    #pragma unroll
    for (int p = 0; p < 2; p++) {
        const int r = rowbase + p * 64 + srow;
        const unsigned short* src = gbase + (size_t)r * ldx + (k0 + ((schunk ^ (srow & 7)) * 8));
        __builtin_amdgcn_global_load_lds((AS1 void*)src,
                                         (AS3 void*)(&lbuf[r * 64 + schunk * 8]),
                                         16, 0, 0);
    }
}

// ---------------- 256x256-tile 4-phase NT GEMM: C[m,n] = sum_k A[m,k]*B[n,k] ----------------
// 512 threads = 8 waves (2M x 4N), BK=64, double-buffered 128 KiB LDS, 16x16x32 MFMA.
// R4-proven schedule: stage tile t+1 spread over P1/P2/P3 (A-h1, B-h0, B-h1), A-h0 of
// tile t+2 at P4, single counted vmcnt(2) at P4 before its barrier (tail: vmcnt(0)).
// Bijective XCD swizzle (grid % 8 == 0).
template<int QH, int RELU, int OUT_BF16>
__global__ __launch_bounds__(512, 2) void gemm256_kernel(
        const unsigned short* __restrict__ A,
        const unsigned short* __restrict__ Bm,   // [Nd, ldb] row-major bf16
        const float* __restrict__ bias,
        const float* __restrict__ qh,            // [32,1024] fp32 raw when QH
        const float* __restrict__ qscale,        // scale1 when QH
        void* __restrict__ Cout,
        int K, int lda, int ldb, int ldc) {
    const int t = threadIdx.x;
    // XCD-bijective remap of the flat workgroup id (nwg divisible by 8)
    const int nx = gridDim.x;
    const int nwg = nx * gridDim.y;
    const int orig = blockIdx.y * nx + blockIdx.x;
    const int q = nwg >> 3;
    const int swz = (orig & 7) * q + (orig >> 3);
    const int tileM = (swz / nx) * 256;
    const int tileN = (swz % nx) * 256;
    const unsigned short* At = A + (size_t)tileM * lda;
    const unsigned short* Bt = Bm + (size_t)tileN * ldb;

    __shared__ unsigned short As[2][256 * 64];
    __shared__ unsigned short Bs[2][256 * 64];

    const int lane = t & 63;
    const int wv = t >> 6;           // 0..7
    const int wm = (wv & 1) * 128;   // wave's 128-row M base
    const int wn = (wv >> 1) * 64;   // wave's 64-row N base
    const int lr = lane & 15;
    const int koff0 = (((lane >> 4) + 0) ^ (lane & 7)) * 8;
    const int koff1 = (((lane >> 4) + 4) ^ (lane & 7)) * 8;

    const int srow = t >> 3;         // 0..63 staging row within 64-row pass
    const int schunk = t & 7;        // staging 8-elem chunk

    floatx4 acc[8][4];
    const floatx4 fzero = {0.f, 0.f, 0.f, 0.f};
    #pragma unroll
    for (int i = 0; i < 8; i++)
        #pragma unroll
        for (int j = 0; j < 4; j++) acc[i][j] = fzero;

    const int NT = K >> 6;           // K-tiles (>= 2 for all call sites)

    // prologue: tile0 (4 halves, oldest in FIFO) + A-h0 of tile1; drain tile0, keep 2 in flight
    stage_half_g(At, lda, As[0], 0,   0, srow, schunk);
    stage_half_g(At, lda, As[0], 128, 0, srow, schunk);
    stage_half_g(Bt, ldb, Bs[0], 0,   0, srow, schunk);
    stage_half_g(Bt, ldb, Bs[0], 128, 0, srow, schunk);
    stage_half_g(At, lda, As[1], 0,  64, srow, schunk);
    asm volatile("s_waitcnt vmcnt(2)" ::: "memory");
    __builtin_amdgcn_s_barrier();

    bf16x8 aR[4][2], bR0[2][2], bR1[2][2];

    for (int tt = 0; tt < NT; ++tt) {
        const int c = tt & 1;
        const unsigned short* Ac = As[c];
        const unsigned short* Bc = Bs[c];
        const int nc = (tt + 1) & 1;
        const int k1 = (tt + 1) << 6;

        // ---- P1: read A-frags 0..3 + B-frags 0..1; stage A-h1(t+1) ----
        #pragma unroll
        for (int i = 0; i < 4; i++) {
            aR[i][0] = *(const bf16x8*)(&Ac[(wm + i * 16 + lr) * 64 + koff0]);
            aR[i][1] = *(const bf16x8*)(&Ac[(wm + i * 16 + lr) * 64 + koff1]);
        }
        #pragma unroll
        for (int j = 0; j < 2; j++) {
            bR0[j][0] = *(const bf16x8*)(&Bc[(wn + j * 16 + lr) * 64 + koff0]);
            bR0[j][1] = *(const bf16x8*)(&Bc[(wn + j * 16 + lr) * 64 + koff1]);
        }
        if (tt + 1 < NT) stage_half_g(At, lda, As[nc], 128, k1, srow, schunk);
        __builtin_amdgcn_s_barrier();
        asm volatile("s_waitcnt lgkmcnt(0)" ::: "memory");
        __builtin_amdgcn_s_setprio(1);
        #pragma unroll
        for (int i = 0; i < 4; i++)
            #pragma unroll
            for (int j = 0; j < 2; j++)
                #pragma unroll
                for (int ks = 0; ks < 2; ks++)
                    acc[i][j] = __builtin_amdgcn_mfma_f32_16x16x32_bf16(
                        aR[i][ks], bR0[j][ks], acc[i][j], 0, 0, 0);
        __builtin_amdgcn_s_setprio(0);
        __builtin_amdgcn_s_barrier();

        // ---- P2: read B-frags 2..3; stage B-h0(t+1) ----
        #pragma unroll
        for (int j = 0; j < 2; j++) {
            bR1[j][0] = *(const bf16x8*)(&Bc[(wn + (j + 2) * 16 + lr) * 64 + koff0]);
            bR1[j][1] = *(const bf16x8*)(&Bc[(wn + (j + 2) * 16 + lr) * 64 + koff1]);
        }
        if (tt + 1 < NT) stage_half_g(Bt, ldb, Bs[nc], 0, k1, srow, schunk);
        __builtin_amdgcn_s_barrier();
        asm volatile("s_waitcnt lgkmcnt(0)" ::: "memory");
        __builtin_amdgcn_s_setprio(1);
        #pragma unroll
        for (int i = 0; i < 4; i++)
            #pragma unroll
            for (int j = 0; j < 2; j++)
                #pragma unroll
                for (int ks = 0; ks < 2; ks++)
                    acc[i][j + 2] = __builtin_amdgcn_mfma_f32_16x16x32_bf16(
                        aR[i][ks], bR1[j][ks], acc[i][j + 2], 0, 0, 0);
        __builtin_amdgcn_s_setprio(0);
        __builtin_amdgcn_s_barrier();

        // ---- P3: read A-frags 4..7 (overwrite aR); stage B-h1(t+1) ----
        #pragma unroll
        for (int i = 0; i < 4; i++) {
            aR[i][0] = *(const bf16x8*)(&Ac[(wm + (i + 4) * 16 + lr) * 64 + koff0]);
            aR[i][1] = *(const bf16x8*)(&Ac[(wm + (i + 4) * 16 + lr) * 64 + koff1]);
        }
        if (tt + 1 < NT) stage_half_g(Bt, ldb, Bs[nc], 128, k1, srow, schunk);
        __builtin_amdgcn_s_barrier();
        asm volatile("s_waitcnt lgkmcnt(0)" ::: "memory");
        __builtin_amdgcn_s_setprio(1);
        #pragma unroll
        for (int i = 0; i < 4; i++)
            #pragma unroll
            for (int j = 0; j < 2; j++)
                #pragma unroll
                for (int ks = 0; ks < 2; ks++)
                    acc[i + 4][j + 2] = __builtin_amdgcn_mfma_f32_16x16x32_bf16(
                        aR[i][ks], bR1[j][ks], acc[i + 4][j + 2], 0, 0, 0);
        __builtin_amdgcn_s_setprio(0);
        __builtin_amdgcn_s_barrier();

        // ---- P4: no ds_read; stage A-h0(t+2) into As[c]; counted vmcnt(2) ----
        if (tt + 2 < NT) {
            stage_half_g(At, lda, As[c], 0, (tt + 2) << 6, srow, schunk);
            asm volatile("s_waitcnt vmcnt(2)" ::: "memory");   // tile t+1 fully landed
        } else if (tt + 1 < NT) {
            asm volatile("s_waitcnt vmcnt(0)" ::: "memory");   // tail drain
        }
        __builtin_amdgcn_s_barrier();
        __builtin_amdgcn_s_setprio(1);
        #pragma unroll
        for (int i = 0; i < 4; i++)
            #pragma unroll
            for (int j = 0; j < 2; j++)
                #pragma unroll
                for (int ks = 0; ks < 2; ks++)
                    acc[i + 4][j] = __builtin_amdgcn_mfma_f32_16x16x32_bf16(
                        aR[i][ks], bR0[j][ks], acc[i + 4][j], 0, 0, 0);
        __builtin_amdgcn_s_setprio(0);
        __builtin_amdgcn_s_barrier();
    }

    // epilogue: D row (M) = (lane>>4)*4 + r, col (N) = lane&15  [m89-verified layout]
    unsigned short* Cb = (unsigned short*)Cout;
    float* Cf = (float*)Cout;
    const float* qhr = QH ? (qh + (size_t)(tileM >> 9) * 1024) : nullptr;
    const int rowHalf = (lane >> 4) * 4;
    #pragma unroll
    for (int j = 0; j < 4; j++) {
        const int col = tileN + wn + j * 16 + lr;
        float bv = RELU ? bias[col] : 0.0f;
        if (QH) bv += qscale[col] * qhr[col];
        #pragma unroll
        for (int i = 0; i < 8; i++) {
            const int row0 = tileM + wm + i * 16 + rowHalf;
            #pragma unroll
            for (int r = 0; r < 4; r++) {
                float val = acc[i][j][r] + bv;
                if (RELU) val = fmaxf(val, 0.0f);
                const size_t off = (size_t)(row0 + r) * ldc + col;
                if (OUT_BF16) Cb[off] = f2bf(val);
                else          Cf[off] = val;
            }
        }
    }
}

// ---------------- 128x128 NT GEMM (m97 structure) — kept for the batched S GEMM ----------------
template<int QH, int RELU, int OUT_BF16>
__global__ __launch_bounds__(256) void gemm_bt_kernel(
        const unsigned short* __restrict__ A,
        const unsigned short* __restrict__ Bm,
        const float* __restrict__ bias,
        const float* __restrict__ qh,
        void* __restrict__ Cout,
        int K, int lda, int ldb, int ldc,
        long strideA, long strideB, long strideC) {
    const int t = threadIdx.x;
    const int bz = blockIdx.z;
    const int tileM = blockIdx.y * 128;
    const int tileN = blockIdx.x * 128;
    const unsigned short* Abase = A + (size_t)bz * strideA;
    const unsigned short* Bbase = Bm + (size_t)bz * strideB;

    __shared__ unsigned short As[128 * 64];
    __shared__ unsigned short Bs[128 * 64];

    const int lane = t & 63;
    const int wv = t >> 6;
    const int wm = (wv & 1) * 64;
    const int wn = (wv >> 1) * 64;
    const int lr = lane & 15;

    const int koff0 = (((lane >> 4) + 0) ^ (lane & 7)) * 8;
    const int koff1 = (((lane >> 4) + 4) ^ (lane & 7)) * 8;

    floatx4 acc[4][4];
    const floatx4 fzero = {0.f, 0.f, 0.f, 0.f};
    #pragma unroll
    for (int i = 0; i < 4; i++)
        #pragma unroll
        for (int j = 0; j < 4; j++) acc[i][j] = fzero;

    const int rowQ = t >> 3;
    const int colSw = ((t & 7) ^ (rowQ & 7)) * 8;

    for (int k0 = 0; k0 < K; k0 += 64) {
        #pragma unroll
        for (int p = 0; p < 4; p++) {
            const int r = p * 32 + rowQ;
            const unsigned short* srcA = Abase + (size_t)(tileM + r) * lda + (k0 + colSw);
            __builtin_amdgcn_global_load_lds((AS1 void*)srcA,
                                             (AS3 void*)(&As[p * 2048 + t * 8]),
                                             16, 0, 0);
        }
        #pragma unroll
        for (int p = 0; p < 4; p++) {
            const int r = p * 32 + rowQ;
            const unsigned short* srcB = Bbase + (size_t)(tileN + r) * ldb + (k0 + colSw);
            __builtin_amdgcn_global_load_lds((AS1 void*)srcB,
                                             (AS3 void*)(&Bs[p * 2048 + t * 8]),
                                             16, 0, 0);
        }
        __syncthreads();

        #pragma unroll
        for (int ks = 0; ks < 2; ks++) {
            const int koff = ks ? koff1 : koff0;
            bf16x8 af[4], bfr[4];
            #pragma unroll
            for (int i = 0; i < 4; i++)
                af[i] = *(const bf16x8*)(&As[(wm + i * 16 + lr) * 64 + koff]);
            #pragma unroll
            for (int j = 0; j < 4; j++)
                bfr[j] = *(const bf16x8*)(&Bs[(wn + j * 16 + lr) * 64 + koff]);
            #pragma unroll
            for (int i = 0; i < 4; i++)
                #pragma unroll
                for (int j = 0; j < 4; j++)
                    acc[i][j] = __builtin_amdgcn_mfma_f32_16x16x32_bf16(
                        af[i], bfr[j], acc[i][j], 0, 0, 0);
        }
        __syncthreads();
    }

    unsigned short* Cb = (unsigned short*)Cout + (size_t)bz * strideC;
    float* Cf = (float*)Cout + (size_t)bz * strideC;
    const float* qhr = QH ? (qh + (size_t)(tileM >> 9) * 1024) : nullptr;
    const int rowHalf = (lane >> 4) * 4;
    #pragma unroll
    for (int j = 0; j < 4; j++) {
        const int col = tileN + wn + j * 16 + lr;
        float bv = RELU ? bias[col] : 0.0f;
        if (QH) bv += qhr[col];
        #pragma unroll
        for (int i = 0; i < 4; i++) {
            const int row0 = tileM + wm + i * 16 + rowHalf;
            #pragma unroll
            for (int r = 0; r < 4; r++) {
                float val = acc[i][j][r] + bv;
                if (RELU) val = fmaxf(val, 0.0f);
                const size_t off = (size_t)(row0 + r) * ldc + col;
                if (OUT_BF16) Cb[off] = f2bf(val);
                else          Cf[off] = val;
            }
        }
    }
}

// ---------------- gather: out[e] = S_flat[idx[e]] ----------------
__global__ __launch_bounds__(256) void gather_kernel(
        const float* __restrict__ S, const int* __restrict__ idx,
        float* __restrict__ out, int E) {
    int e = blockIdx.x * 256 + threadIdx.x;
    if (e < E) out[e] = S[idx[e]];
}

extern "C" void kernel_launch(void* const* d_in, const int* in_sizes, int n_in,
                              void* d_out, int out_size, void* d_ws, size_t ws_size,
                              hipStream_t stream) {
    const float* node = (const float*)d_in[0];   // [32,512,2048]
    const float* qf   = (const float*)d_in[1];   // [32,1024]
    const int*   idx  = (const int*)d_in[2];     // [1048576]
    const float* v1   = (const float*)d_in[3];   // [1024,3072]
    const float* g1   = (const float*)d_in[4];
    const float* b1   = (const float*)d_in[5];
    const float* v2   = (const float*)d_in[6];   // [1024,1024]
    const float* g2   = (const float*)d_in[7];
    const float* b2   = (const float*)d_in[8];
    float* out = (float*)d_out;

    // workspace carve (all offsets 256B aligned); S aliases nodesB (dead after GEMM1)
    char* ws = (char*)d_ws;
    unsigned short* W1     = (unsigned short*)(ws);              // 6,291,456 B
    unsigned short* W2     = (unsigned short*)(ws + 6291456);    // 2,097,152 B
    unsigned short* nodesB = (unsigned short*)(ws + 8388608);    // 67,108,864 B (reused as S)
    float*          S      = (float*)(ws + 8388608);             // 33,554,432 B (alias)
    unsigned short* h1     = (unsigned short*)(ws + 75563008);   // 33,554,432 B
    unsigned short* h2     = (unsigned short*)(ws + 109117440);  // 33,554,432 B
    float*          scale1 = (float*)(ws + 142671872);           // 4,096 B
    float*          scale2 = (float*)(ws + 142675968);           // 4,096 B
    float*          qh     = (float*)(ws + 142680064);           // 131,072 B (raw, unscaled)

    // prep: fused {weight-norm x2, folded q@W1b^T (raw), fp32->bf16 node convert}
    hipMemsetAsync(qh, 0, 131072, stream);
    prep_kernel<<<6208, 256, 0, stream>>>(v1, g1, W1, scale1,
                                          v2, g2, W2, scale2, qf, qh,
                                          node, nodesB);

    // h1 = relu(nodes @ W1a^T + scale1*qhraw[b] + b1)   M=16384 N=1024 K=2048 (ldb=3072)
    gemm256_kernel<1, 1, 1><<<dim3(4, 64), 512, 0, stream>>>(
        nodesB, W1, b1, qh, scale1, h1, 2048, 2048, 3072, 1024);
    // h2 = relu(h1 @ W2^T + b2)                          M=16384 N=1024 K=1024
    gemm256_kernel<0, 1, 1><<<dim3(4, 64), 512, 0, stream>>>(
        h1, W2, b2, nullptr, nullptr, h2, 1024, 1024, 1024, 1024);
    // S[b] = h2[b] @ h2[b]^T                             batched 512x512, K=1024, fp32 out
    gemm_bt_kernel<0, 0, 0><<<dim3(4, 4, 32), 256, 0, stream>>>(
        h2, h2, nullptr, nullptr, S, 1024, 1024, 1024, 512,
        512L * 1024L, 512L * 1024L, 512L * 512L);
    // gather
    gather_kernel<<<4096, 256, 0, stream>>>(S, idx, out, 1048576);
}